// Round 3
// baseline (659.538 us; speedup 1.0000x reference)
//
#include <hip/hip_runtime.h>

// BISECTION ROUND: pure-f32 VALU pipeline (no MFMA, no bf16, no in-place
// aliasing). Isolates whether round-2's 0.609 absmax came from the MFMA
// fragment path or from the shared CSR/agg/LN structure.

#define HID 128

// ---------------- CSR build ----------------

__global__ __launch_bounds__(256) void deg_kernel(const int* __restrict__ dst, int* __restrict__ deg, int E) {
    int e = blockIdx.x * 256 + threadIdx.x;
    if (e < E) atomicAdd(&deg[dst[e]], 1);
}

__global__ __launch_bounds__(256) void scan1_kernel(const int* __restrict__ deg, int* __restrict__ incl,
                                                    int* __restrict__ blksum, int N) {
    __shared__ int sm[256];
    int i = blockIdx.x * 256 + threadIdx.x;
    int v = (i < N) ? deg[i] : 0;
    sm[threadIdx.x] = v;
    __syncthreads();
    for (int d = 1; d < 256; d <<= 1) {
        int t = (threadIdx.x >= d) ? sm[threadIdx.x - d] : 0;
        __syncthreads();
        sm[threadIdx.x] += t;
        __syncthreads();
    }
    if (i < N) incl[i] = sm[threadIdx.x];
    if (threadIdx.x == 255) blksum[blockIdx.x] = sm[255];
}

__global__ __launch_bounds__(256) void scan2_kernel(const int* __restrict__ blksum, int* __restrict__ blkoff, int nb) {
    __shared__ int sm[256];
    int t = threadIdx.x;
    int v = (t < nb) ? blksum[t] : 0;
    sm[t] = v;
    __syncthreads();
    for (int d = 1; d < 256; d <<= 1) {
        int u = (t >= d) ? sm[t - d] : 0;
        __syncthreads();
        sm[t] += u;
        __syncthreads();
    }
    if (t < nb) blkoff[t] = sm[t] - v;  // exclusive
}

__global__ __launch_bounds__(256) void scan3_kernel(const int* __restrict__ incl, const int* __restrict__ deg,
                                                    const int* __restrict__ blkoff, int* __restrict__ rowptr,
                                                    float* __restrict__ invdeg, int N, int E) {
    int i = blockIdx.x * 256 + threadIdx.x;
    if (i < N) {
        rowptr[i] = incl[i] - deg[i] + blkoff[blockIdx.x];
        invdeg[i] = 1.0f / fmaxf((float)deg[i], 1.0f);
    }
    if (i == 0) rowptr[N] = E;
}

__global__ __launch_bounds__(256) void fill_kernel(const int* __restrict__ src, const int* __restrict__ dst,
                                                   const int* __restrict__ rowptr, int* __restrict__ cnt,
                                                   int* __restrict__ colA, int E) {
    int e = blockIdx.x * 256 + threadIdx.x;
    if (e < E) {
        int d = dst[e];
        int p = rowptr[d] + atomicAdd(&cnt[d], 1);
        colA[p] = src[e];
    }
}

__global__ __launch_bounds__(256) void sort_kernel(const int* __restrict__ rowptr, int* __restrict__ colA, int N) {
    int i = blockIdx.x * 256 + threadIdx.x;
    if (i >= N) return;
    int b = rowptr[i], e = rowptr[i + 1];
    for (int j = b + 1; j < e; j++) {
        int key = colA[j];
        int k = j - 1;
        while (k >= b && colA[k] > key) { colA[k + 1] = colA[k]; k--; }
        colA[k + 1] = key;
    }
}

// ---------------- f32 mean aggregation (wave per node, lane = 2 cols) ----------------

__global__ __launch_bounds__(256) void aggf_kernel(const float* __restrict__ h, const int* __restrict__ rowptr,
                                                   const int* __restrict__ colA, const float* __restrict__ invdeg,
                                                   float* __restrict__ agg, int N) {
    int wid = (blockIdx.x * 256 + threadIdx.x) >> 6;
    int lane = threadIdx.x & 63;
    if (wid >= N) return;
    int b = rowptr[wid], e = rowptr[wid + 1];
    float ax = 0.f, ay = 0.f;
    for (int j = b; j < e; j++) {
        int s = colA[j];
        float2 v = *(const float2*)(h + s * HID + lane * 2);
        ax += v.x;
        ay += v.y;
    }
    float id = invdeg[wid];
    float2 o;
    o.x = ax * id;
    o.y = ay * id;
    *(float2*)(agg + wid * HID + lane * 2) = o;
}

// ---------------- f32 VALU GEMM + fused epilogue ----------------
// Block: 256 threads -> 8 rows x 128 cols. Thread: col = tid&127, rgrp = tid>>7,
// owns rows rgrp*4 + j (j=0..3), one column each.
// K=128: out = A0 @ W0 + bias                     (input projection)
// K=256: z = A0@W0 + A1@W1 + bias; relu; + A1 row (residual); LayerNorm -> out

template <int K, bool FUSE>
__global__ __launch_bounds__(256) void gemmv_kernel(
    const float* __restrict__ A0, const float* __restrict__ A1,
    const float* __restrict__ W0, const float* __restrict__ W1,
    const float* __restrict__ bias, const float* __restrict__ lng, const float* __restrict__ lnb,
    float* __restrict__ out, int N) {
    __shared__ float a0_lds[8][HID];
    __shared__ float a1_lds[(K == 256) ? 8 : 1][HID];
    __shared__ float sm_s[4][4];
    __shared__ float sm_s2[4][4];

    const int tid = threadIdx.x;
    const int col = tid & 127;
    const int rgrp = tid >> 7;
    const int row0 = blockIdx.x * 8;

    // stage A rows (clamped for tail)
    #pragma unroll
    for (int it = 0; it < 4; it++) {
        int idx = it * 256 + tid;
        int r = idx >> 7, c = idx & 127;
        int gr = row0 + r;
        if (gr >= N) gr = N - 1;
        a0_lds[r][c] = A0[(size_t)gr * HID + c];
        if constexpr (K == 256) a1_lds[r][c] = A1[(size_t)gr * HID + c];
    }
    __syncthreads();

    float acc[4] = {0.f, 0.f, 0.f, 0.f};
    #pragma unroll 4
    for (int k = 0; k < HID; k++) {
        float w = W0[k * HID + col];
        #pragma unroll
        for (int j = 0; j < 4; j++) acc[j] += a0_lds[rgrp * 4 + j][k] * w;
    }
    if constexpr (K == 256) {
        #pragma unroll 4
        for (int k = 0; k < HID; k++) {
            float w = W1[k * HID + col];
            #pragma unroll
            for (int j = 0; j < 4; j++) acc[j] += a1_lds[rgrp * 4 + j][k] * w;
        }
    }

    float z[4];
    const float bcol = bias[col];
    #pragma unroll
    for (int j = 0; j < 4; j++) {
        z[j] = acc[j] + bcol;
        if constexpr (FUSE) {
            z[j] = fmaxf(z[j], 0.f) + a1_lds[rgrp * 4 + j][col];  // + h_in residual
        }
    }

    if constexpr (FUSE) {
        // per-row LayerNorm: each row's 128 cols live in exactly 2 waves
        float s[4], s2[4];
        #pragma unroll
        for (int j = 0; j < 4; j++) { s[j] = z[j]; s2[j] = z[j] * z[j]; }
        #pragma unroll
        for (int d = 1; d < 64; d <<= 1) {
            #pragma unroll
            for (int j = 0; j < 4; j++) {
                s[j] += __shfl_xor(s[j], d);
                s2[j] += __shfl_xor(s2[j], d);
            }
        }
        const int wv = tid >> 6;
        if ((tid & 63) == 0) {
            #pragma unroll
            for (int j = 0; j < 4; j++) { sm_s[wv][j] = s[j]; sm_s2[wv][j] = s2[j]; }
        }
        __syncthreads();
        const float gcol = lng[col], bcol2 = lnb[col];
        #pragma unroll
        for (int j = 0; j < 4; j++) {
            float S = sm_s[rgrp * 2][j] + sm_s[rgrp * 2 + 1][j];
            float S2 = sm_s2[rgrp * 2][j] + sm_s2[rgrp * 2 + 1][j];
            float mu = S * (1.f / 128.f);
            float var = S2 * (1.f / 128.f) - mu * mu;
            float rs = rsqrtf(var + 1e-5f);
            int gr = row0 + rgrp * 4 + j;
            if (gr < N) out[(size_t)gr * HID + col] = (z[j] - mu) * rs * gcol + bcol2;
        }
    } else {
        #pragma unroll
        for (int j = 0; j < 4; j++) {
            int gr = row0 + rgrp * 4 + j;
            if (gr < N) out[(size_t)gr * HID + col] = z[j];
        }
    }
}

// ---------------- launch ----------------

extern "C" void kernel_launch(void* const* d_in, const int* in_sizes, int n_in,
                              void* d_out, int out_size, void* d_ws, size_t ws_size,
                              hipStream_t stream) {
    const float* x = (const float*)d_in[0];
    const int* ei = (const int*)d_in[1];
    const float* inW = (const float*)d_in[2];
    const float* inb = (const float*)d_in[3];
    const float* Wl = (const float*)d_in[4];
    const float* bl = (const float*)d_in[5];
    const float* Wr = (const float*)d_in[6];
    const float* lng = (const float*)d_in[7];
    const float* lnb = (const float*)d_in[8];
    float* out = (float*)d_out;

    const int N = in_sizes[0] / HID;
    const int E = in_sizes[1] / 2;
    const int NL = 3;
    const int* src = ei;
    const int* dst = ei + E;

    char* w = (char*)d_ws;
    auto alloc = [&](size_t bytes) -> char* {
        char* p = w;
        w += (bytes + 255) & ~(size_t)255;
        return p;
    };
    int* degcnt = (int*)alloc((size_t)2 * N * 4);  // single memset covers both
    int* deg = degcnt;
    int* cnt = degcnt + N;
    int* rowptr = (int*)alloc((N + 1) * 4);
    int* incl = (int*)alloc(N * 4);
    int* blksum = (int*)alloc(256 * 4);
    int* blkoff = (int*)alloc(256 * 4);
    int* colA = (int*)alloc((size_t)E * 4);
    float* invdeg = (float*)alloc(N * 4);
    float* H0 = (float*)alloc((size_t)N * HID * 4);
    float* H1 = (float*)alloc((size_t)N * HID * 4);
    float* AGG = (float*)alloc((size_t)N * HID * 4);

    const int nbN = (N + 255) / 256;
    const int nbE = (E + 255) / 256;

    hipMemsetAsync(degcnt, 0, (size_t)2 * N * 4, stream);

    deg_kernel<<<nbE, 256, 0, stream>>>(dst, deg, E);
    scan1_kernel<<<nbN, 256, 0, stream>>>(deg, incl, blksum, N);
    scan2_kernel<<<1, 256, 0, stream>>>(blksum, blkoff, nbN);
    scan3_kernel<<<nbN, 256, 0, stream>>>(incl, deg, blkoff, rowptr, invdeg, N, E);
    fill_kernel<<<nbE, 256, 0, stream>>>(src, dst, rowptr, cnt, colA, E);
    sort_kernel<<<nbN, 256, 0, stream>>>(rowptr, colA, N);

    const int gb = (N + 7) / 8;
    const int aggblocks = (N * 64 + 255) / 256;

    // input projection: H0 = x @ in_W + in_b
    gemmv_kernel<128, false><<<gb, 256, 0, stream>>>(x, nullptr, inW, nullptr, inb,
                                                     nullptr, nullptr, H0, N);

    float* Hcur = H0;
    float* Hnext = H1;
    for (int i = 0; i < NL; i++) {
        aggf_kernel<<<aggblocks, 256, 0, stream>>>(Hcur, rowptr, colA, invdeg, AGG, N);
        float* dsti = (i == NL - 1) ? out : Hnext;
        gemmv_kernel<256, true><<<gb, 256, 0, stream>>>(AGG, Hcur,
                                                        Wl + (size_t)i * HID * HID,
                                                        Wr + (size_t)i * HID * HID,
                                                        bl + i * HID, lng + i * HID, lnb + i * HID,
                                                        dsti, N);
        float* t = Hcur; Hcur = Hnext; Hnext = t;
    }
}

// Round 6
// 507.386 us; speedup vs baseline: 1.2999x; 1.2999x over previous
//
#include <hip/hip_runtime.h>

// SAGEConv stack on MI355X — f32 VALU pipeline (proven correct in round 3),
// optimized: 4x4 register-blocked GEMM (84% FMA issue), f16 shadow of h for
// the aggregation gather (halves gather bytes; GEMM/residual stay f32),
// CSR without sort, fused bias+relu+residual+LayerNorm epilogue via shfl.

typedef _Float16 f16;
typedef __attribute__((ext_vector_type(2))) _Float16 f16x2;
typedef __attribute__((ext_vector_type(4))) _Float16 f16x4;
typedef __attribute__((ext_vector_type(4))) float f32x4;

#define HID 128

// ---------------- CSR build ----------------

__global__ __launch_bounds__(256) void deg_kernel(const int* __restrict__ dst, int* __restrict__ deg, int E) {
    int e = blockIdx.x * 256 + threadIdx.x;
    if (e < E) atomicAdd(&deg[dst[e]], 1);
}

__global__ __launch_bounds__(256) void scan1_kernel(const int* __restrict__ deg, int* __restrict__ incl,
                                                    int* __restrict__ blksum, int N) {
    __shared__ int sm[256];
    int i = blockIdx.x * 256 + threadIdx.x;
    int v = (i < N) ? deg[i] : 0;
    sm[threadIdx.x] = v;
    __syncthreads();
    for (int d = 1; d < 256; d <<= 1) {
        int t = (threadIdx.x >= d) ? sm[threadIdx.x - d] : 0;
        __syncthreads();
        sm[threadIdx.x] += t;
        __syncthreads();
    }
    if (i < N) incl[i] = sm[threadIdx.x];
    if (threadIdx.x == 255) blksum[blockIdx.x] = sm[255];
}

__global__ __launch_bounds__(256) void scan2_kernel(const int* __restrict__ blksum, int* __restrict__ blkoff, int nb) {
    __shared__ int sm[256];
    int t = threadIdx.x;
    int v = (t < nb) ? blksum[t] : 0;
    sm[t] = v;
    __syncthreads();
    for (int d = 1; d < 256; d <<= 1) {
        int u = (t >= d) ? sm[t - d] : 0;
        __syncthreads();
        sm[t] += u;
        __syncthreads();
    }
    if (t < nb) blkoff[t] = sm[t] - v;  // exclusive
}

__global__ __launch_bounds__(256) void scan3_kernel(const int* __restrict__ incl, const int* __restrict__ deg,
                                                    const int* __restrict__ blkoff, int* __restrict__ rowptr,
                                                    float* __restrict__ invdeg, int N, int E) {
    int i = blockIdx.x * 256 + threadIdx.x;
    if (i < N) {
        rowptr[i] = incl[i] - deg[i] + blkoff[blockIdx.x];
        invdeg[i] = 1.0f / fmaxf((float)deg[i], 1.0f);
    }
    if (i == 0) rowptr[N] = E;
}

__global__ __launch_bounds__(256) void fill_kernel(const int* __restrict__ src, const int* __restrict__ dst,
                                                   const int* __restrict__ rowptr, int* __restrict__ cnt,
                                                   int* __restrict__ colA, int E) {
    int e = blockIdx.x * 256 + threadIdx.x;
    if (e < E) {
        int d = dst[e];
        int p = rowptr[d] + atomicAdd(&cnt[d], 1);
        colA[p] = src[e];
    }
}

// ---------------- mean aggregation (wave/node, f16 gather -> f32 out) ----------------

__global__ __launch_bounds__(256) void aggh_kernel(const f16* __restrict__ h16, const int* __restrict__ rowptr,
                                                   const int* __restrict__ colA, const float* __restrict__ invdeg,
                                                   float* __restrict__ agg, int N) {
    int wid = (blockIdx.x * 256 + threadIdx.x) >> 6;
    int lane = threadIdx.x & 63;
    if (wid >= N) return;
    int b = rowptr[wid], e = rowptr[wid + 1];
    float ax = 0.f, ay = 0.f;
    for (int j = b; j < e; j++) {
        int s = colA[j];
        f16x2 v = *(const f16x2*)(h16 + (size_t)s * HID + lane * 2);
        ax += (float)v[0];
        ay += (float)v[1];
    }
    float id = invdeg[wid];
    float2 o;
    o.x = ax * id;
    o.y = ay * id;
    *(float2*)(agg + (size_t)wid * HID + lane * 2) = o;
}

// ---------------- f32 GEMM, 4x4 register-blocked, fused epilogue ----------------
// Block: 256 threads, 32 rows x 128 cols. Thread: cq=tid&31 -> cols 4cq..4cq+3,
// rg=tid>>5 -> rows 4rg..4rg+3. Per 4-k step: 4 ds_read_b128 (a, broadcast) +
// 4 global b128 (w, 8x L1 reuse) + 64 FMA.
// K=128: out = A0@W0 + bias (input projection).
// K=256: z = A0@W0 + A1@W1 + bias; relu; + resid (f32 h_in); LayerNorm.
// In-place safety (middle layers: out32==A1==resid): each thread reads resid
// for exactly the (row,col) set it later writes; staging reads only own-block
// rows before any write; blocks own disjoint row sets.

template <int K, bool FUSE, bool LAST>
__global__ __launch_bounds__(256) void gemmf_kernel(
    const float* __restrict__ A0, const float* __restrict__ A1,
    const float* __restrict__ W0, const float* __restrict__ W1,
    const float* __restrict__ bias, const float* __restrict__ lng, const float* __restrict__ lnb,
    const float* resid, float* out32, f16* out16, int N) {
    __shared__ float a_lds[32][K];

    const int tid = threadIdx.x;
    const int cq = tid & 31;
    const int rg = tid >> 5;
    const int row0 = blockIdx.x * 32;

    // stage A rows (f32, clamped for tail)
    constexpr int QPR = K / 4;
    for (int c = tid; c < 32 * QPR; c += 256) {
        int r = c / QPR, q = c % QPR;
        int gr = row0 + r;
        if (gr >= N) gr = N - 1;
        f32x4 v;
        if constexpr (K == 256) {
            if (q >= 32) v = *(const f32x4*)(A1 + (size_t)gr * HID + (q - 32) * 4);
            else         v = *(const f32x4*)(A0 + (size_t)gr * HID + q * 4);
        } else {
            v = *(const f32x4*)(A0 + (size_t)gr * HID + q * 4);
        }
        *(f32x4*)&a_lds[r][q * 4] = v;
    }
    __syncthreads();

    float acc[4][4] = {};

    #pragma unroll 2
    for (int k = 0; k < 128; k += 4) {
        f32x4 a[4];
        #pragma unroll
        for (int j = 0; j < 4; j++) a[j] = *(const f32x4*)&a_lds[rg * 4 + j][k];
        #pragma unroll
        for (int kk = 0; kk < 4; kk++) {
            f32x4 w = *(const f32x4*)(W0 + (size_t)(k + kk) * HID + cq * 4);
            #pragma unroll
            for (int j = 0; j < 4; j++) {
                float av = a[j][kk];
                acc[j][0] += av * w[0];
                acc[j][1] += av * w[1];
                acc[j][2] += av * w[2];
                acc[j][3] += av * w[3];
            }
        }
    }
    if constexpr (K == 256) {
        #pragma unroll 2
        for (int k = 0; k < 128; k += 4) {
            f32x4 a[4];
            #pragma unroll
            for (int j = 0; j < 4; j++) a[j] = *(const f32x4*)&a_lds[rg * 4 + j][128 + k];
            #pragma unroll
            for (int kk = 0; kk < 4; kk++) {
                f32x4 w = *(const f32x4*)(W1 + (size_t)(k + kk) * HID + cq * 4);
                #pragma unroll
                for (int j = 0; j < 4; j++) {
                    float av = a[j][kk];
                    acc[j][0] += av * w[0];
                    acc[j][1] += av * w[1];
                    acc[j][2] += av * w[2];
                    acc[j][3] += av * w[3];
                }
            }
        }
    }

    // epilogue
    f32x4 bv = *(const f32x4*)(bias + cq * 4);
    f32x4 gv = {}, lv = {};
    if constexpr (FUSE) {
        gv = *(const f32x4*)(lng + cq * 4);
        lv = *(const f32x4*)(lnb + cq * 4);
    }
    #pragma unroll
    for (int j = 0; j < 4; j++) {
        int gr = row0 + rg * 4 + j;
        int grc = (gr < N) ? gr : (N - 1);
        f32x4 z;
        #pragma unroll
        for (int c = 0; c < 4; c++) z[c] = acc[j][c] + bv[c];
        if constexpr (FUSE) {
            f32x4 res = *(const f32x4*)(resid + (size_t)grc * HID + cq * 4);
            #pragma unroll
            for (int c = 0; c < 4; c++) z[c] = fmaxf(z[c], 0.f) + res[c];
            // row LN: 32 threads (same rg) hold the row's 128 cols; d<=16 shfl_xor
            // stays within the aligned 32-lane group.
            float s = z[0] + z[1] + z[2] + z[3];
            float s2 = z[0] * z[0] + z[1] * z[1] + z[2] * z[2] + z[3] * z[3];
            #pragma unroll
            for (int d = 1; d < 32; d <<= 1) {
                s += __shfl_xor(s, d);
                s2 += __shfl_xor(s2, d);
            }
            float mu = s * (1.f / 128.f);
            float var = s2 * (1.f / 128.f) - mu * mu;
            float rs = rsqrtf(var + 1e-5f);
            #pragma unroll
            for (int c = 0; c < 4; c++) z[c] = (z[c] - mu) * rs * gv[c] + lv[c];
        }
        if (gr < N) {
            *(f32x4*)(out32 + (size_t)gr * HID + cq * 4) = z;
            if constexpr (!LAST) {
                f16x4 p;
                #pragma unroll
                for (int c = 0; c < 4; c++) p[c] = (f16)z[c];
                *(f16x4*)(out16 + (size_t)gr * HID + cq * 4) = p;
            }
        }
    }
}

// ---------------- launch ----------------

extern "C" void kernel_launch(void* const* d_in, const int* in_sizes, int n_in,
                              void* d_out, int out_size, void* d_ws, size_t ws_size,
                              hipStream_t stream) {
    const float* x = (const float*)d_in[0];
    const int* ei = (const int*)d_in[1];
    const float* inW = (const float*)d_in[2];
    const float* inb = (const float*)d_in[3];
    const float* Wl = (const float*)d_in[4];
    const float* bl = (const float*)d_in[5];
    const float* Wr = (const float*)d_in[6];
    const float* lng = (const float*)d_in[7];
    const float* lnb = (const float*)d_in[8];
    float* out = (float*)d_out;

    const int N = in_sizes[0] / HID;
    const int E = in_sizes[1] / 2;
    const int NL = 3;
    const int* src = ei;
    const int* dst = ei + E;

    char* w = (char*)d_ws;
    auto alloc = [&](size_t bytes) -> char* {
        char* p = w;
        w += (bytes + 255) & ~(size_t)255;
        return p;
    };
    int* degcnt = (int*)alloc((size_t)2 * N * 4);  // one alloc: single memset covers both
    int* deg = degcnt;
    int* cnt = degcnt + N;
    int* rowptr = (int*)alloc((N + 1) * 4);
    int* incl = (int*)alloc(N * 4);
    int* blksum = (int*)alloc(256 * 4);
    int* blkoff = (int*)alloc(256 * 4);
    int* colA = (int*)alloc((size_t)E * 4);
    float* invdeg = (float*)alloc(N * 4);
    float* H32 = (float*)alloc((size_t)N * HID * 4);   // f32 h (GEMM A1 + residual)
    f16* H16 = (f16*)alloc((size_t)N * HID * 2);       // f16 shadow (agg gather only)
    float* AGG = (float*)alloc((size_t)N * HID * 4);   // f32 aggregate (GEMM A0)

    const int nbN = (N + 255) / 256;
    const int nbE = (E + 255) / 256;

    hipMemsetAsync(degcnt, 0, (size_t)2 * N * 4, stream);

    deg_kernel<<<nbE, 256, 0, stream>>>(dst, deg, E);
    scan1_kernel<<<nbN, 256, 0, stream>>>(deg, incl, blksum, N);
    scan2_kernel<<<1, 256, 0, stream>>>(blksum, blkoff, nbN);
    scan3_kernel<<<nbN, 256, 0, stream>>>(incl, deg, blkoff, rowptr, invdeg, N, E);
    fill_kernel<<<nbE, 256, 0, stream>>>(src, dst, rowptr, cnt, colA, E);
    // no sort: agg f32 sum order varies ~1e-6; validation is threshold-based

    const int gb = (N + 31) / 32;
    const int aggblocks = (N * 64 + 255) / 256;

    // input projection: h = x @ in_W + in_b  -> H32 + H16
    gemmf_kernel<128, false, false><<<gb, 256, 0, stream>>>(
        x, nullptr, inW, nullptr, inb, nullptr, nullptr, nullptr, H32, H16, N);

    for (int i = 0; i < NL; i++) {
        aggh_kernel<<<aggblocks, 256, 0, stream>>>(H16, rowptr, colA, invdeg, AGG, N);
        if (i == NL - 1) {
            gemmf_kernel<256, true, true><<<gb, 256, 0, stream>>>(
                AGG, H32, Wl + (size_t)i * HID * HID, Wr + (size_t)i * HID * HID,
                bl + i * HID, lng + i * HID, lnb + i * HID, H32, out, nullptr, N);
        } else {
            // in-place h update (own-(row,col)-only reads precede writes per thread)
            gemmf_kernel<256, true, false><<<gb, 256, 0, stream>>>(
                AGG, H32, Wl + (size_t)i * HID * HID, Wr + (size_t)i * HID * HID,
                bl + i * HID, lng + i * HID, lnb + i * HID, H32, H32, H16, N);
        }
    }
}

// Round 7
// 336.741 us; speedup vs baseline: 1.9586x; 1.5068x over previous
//
#include <hip/hip_runtime.h>

// SAGEConv stack on MI355X — f32-accumulate pipeline (proven correct r3/r6),
// GEMMs via packed-f16 v_dot2_f32_f16 (2 MACs/inst, f16 A-tile in LDS for
// occupancy), k-pair-interleaved pre-packed W, aggregation gather unrolled x4,
// fused bias+relu+residual(f32)+LayerNorm epilogue.

typedef _Float16 f16;
typedef __attribute__((ext_vector_type(2))) _Float16 f16x2;
typedef __attribute__((ext_vector_type(4))) _Float16 f16x4;
typedef __attribute__((ext_vector_type(8))) _Float16 f16x8;
typedef __attribute__((ext_vector_type(4))) float f32x4;

#define HID 128

static __device__ __forceinline__ float dot2(f16x2 a, f16x2 b, float c) {
#if __has_builtin(__builtin_amdgcn_fdot2)
    return __builtin_amdgcn_fdot2(a, b, c, false);
#else
    return c + (float)a[0] * (float)b[0] + (float)a[1] * (float)b[1];
#endif
}

// ---------------- CSR build ----------------

__global__ __launch_bounds__(256) void deg_kernel(const int* __restrict__ dst, int* __restrict__ deg, int E) {
    int e = blockIdx.x * 256 + threadIdx.x;
    if (e < E) atomicAdd(&deg[dst[e]], 1);
}

__global__ __launch_bounds__(256) void scan1_kernel(const int* __restrict__ deg, int* __restrict__ incl,
                                                    int* __restrict__ blksum, int N) {
    __shared__ int sm[256];
    int i = blockIdx.x * 256 + threadIdx.x;
    int v = (i < N) ? deg[i] : 0;
    sm[threadIdx.x] = v;
    __syncthreads();
    for (int d = 1; d < 256; d <<= 1) {
        int t = (threadIdx.x >= d) ? sm[threadIdx.x - d] : 0;
        __syncthreads();
        sm[threadIdx.x] += t;
        __syncthreads();
    }
    if (i < N) incl[i] = sm[threadIdx.x];
    if (threadIdx.x == 255) blksum[blockIdx.x] = sm[255];
}

__global__ __launch_bounds__(256) void scan2_kernel(const int* __restrict__ blksum, int* __restrict__ blkoff, int nb) {
    __shared__ int sm[256];
    int t = threadIdx.x;
    int v = (t < nb) ? blksum[t] : 0;
    sm[t] = v;
    __syncthreads();
    for (int d = 1; d < 256; d <<= 1) {
        int u = (t >= d) ? sm[t - d] : 0;
        __syncthreads();
        sm[t] += u;
        __syncthreads();
    }
    if (t < nb) blkoff[t] = sm[t] - v;  // exclusive
}

__global__ __launch_bounds__(256) void scan3_kernel(const int* __restrict__ incl, const int* __restrict__ deg,
                                                    const int* __restrict__ blkoff, int* __restrict__ rowptr,
                                                    float* __restrict__ invdeg, int N, int E) {
    int i = blockIdx.x * 256 + threadIdx.x;
    if (i < N) {
        rowptr[i] = incl[i] - deg[i] + blkoff[blockIdx.x];
        invdeg[i] = 1.0f / fmaxf((float)deg[i], 1.0f);
    }
    if (i == 0) rowptr[N] = E;
}

__global__ __launch_bounds__(256) void fill_kernel(const int* __restrict__ src, const int* __restrict__ dst,
                                                   const int* __restrict__ rowptr, int* __restrict__ cnt,
                                                   int* __restrict__ colA, int E) {
    int e = blockIdx.x * 256 + threadIdx.x;
    if (e < E) {
        int d = dst[e];
        int p = rowptr[d] + atomicAdd(&cnt[d], 1);
        colA[p] = src[e];
    }
}

// ---------------- prep: x -> f16, W -> k-pair-interleaved f16 ----------------

__global__ __launch_bounds__(256) void cvtx_kernel(const float* __restrict__ x, f16* __restrict__ x16, int n4) {
    int i = blockIdx.x * 256 + threadIdx.x;
    if (i >= n4) return;
    f32x4 v = *(const f32x4*)(x + (size_t)i * 4);
    f16x4 o;
    o[0] = (f16)v[0]; o[1] = (f16)v[1]; o[2] = (f16)v[2]; o[3] = (f16)v[3];
    *(f16x4*)(x16 + (size_t)i * 4) = o;
}

// Wp layout: [kp][c][2] f16 — pair (W[2kp][c], W[2kp+1][c]).
// proj blob: kp in [0,64) from inW. layer blob l: kp in [0,128); k<128 Wl, else Wr.
__global__ __launch_bounds__(256) void wpack_kernel(const float* __restrict__ inW, const float* __restrict__ Wl,
                                                    const float* __restrict__ Wr, f16* __restrict__ Wp0,
                                                    f16* __restrict__ WpL, int nlayers) {
    int idx = blockIdx.x * 256 + threadIdx.x;
    int total = 64 * HID + nlayers * HID * HID;  // pair-slots
    if (idx >= total) return;
    if (idx < 64 * HID) {
        int kp = idx / HID, c = idx % HID;
        Wp0[idx * 2 + 0] = (f16)inW[(2 * kp) * HID + c];
        Wp0[idx * 2 + 1] = (f16)inW[(2 * kp + 1) * HID + c];
    } else {
        int r0 = idx - 64 * HID;
        int l = r0 / (HID * HID);
        int r = r0 % (HID * HID);
        int kp = r / HID, c = r % HID;
        int k0 = 2 * kp;
        const float* W = (k0 < HID) ? (Wl + (size_t)l * HID * HID + (size_t)k0 * HID)
                                    : (Wr + (size_t)l * HID * HID + (size_t)(k0 - HID) * HID);
        WpL[(size_t)r0 * 2 + 0] = (f16)W[c];
        WpL[(size_t)r0 * 2 + 1] = (f16)W[HID + c];
    }
}

// ---------------- mean aggregation (wave/node, f16 gather, x4 unroll) ----------------

__global__ __launch_bounds__(256) void aggh_kernel(const f16* __restrict__ h16, const int* __restrict__ rowptr,
                                                   const int* __restrict__ colA, const float* __restrict__ invdeg,
                                                   f16* __restrict__ agg, int N) {
    int wid = (blockIdx.x * 256 + threadIdx.x) >> 6;
    int lane = threadIdx.x & 63;
    if (wid >= N) return;
    int b = rowptr[wid], e = rowptr[wid + 1];
    float ax = 0.f, ay = 0.f;
    int j = b;
    for (; j + 4 <= e; j += 4) {  // 4 row-loads in flight per iteration
        int s0 = colA[j], s1 = colA[j + 1], s2 = colA[j + 2], s3 = colA[j + 3];
        f16x2 v0 = *(const f16x2*)(h16 + (size_t)s0 * HID + lane * 2);
        f16x2 v1 = *(const f16x2*)(h16 + (size_t)s1 * HID + lane * 2);
        f16x2 v2 = *(const f16x2*)(h16 + (size_t)s2 * HID + lane * 2);
        f16x2 v3 = *(const f16x2*)(h16 + (size_t)s3 * HID + lane * 2);
        ax += (float)v0[0] + (float)v1[0] + (float)v2[0] + (float)v3[0];
        ay += (float)v0[1] + (float)v1[1] + (float)v2[1] + (float)v3[1];
    }
    for (; j < e; j++) {
        int s = colA[j];
        f16x2 v = *(const f16x2*)(h16 + (size_t)s * HID + lane * 2);
        ax += (float)v[0];
        ay += (float)v[1];
    }
    float id = invdeg[wid];
    f16x2 o;
    o[0] = (f16)(ax * id);
    o[1] = (f16)(ay * id);
    *(f16x2*)(agg + (size_t)wid * HID + lane * 2) = o;
}

// ---------------- dot2-f16 GEMM, 4x4 register-blocked, fused epilogue ----------------
// Block: 256 threads, 32 rows x 128 cols. Thread: cq=tid&31 -> cols 4cq..4cq+3,
// rg=tid>>5 -> rows 4rg..4rg+3. Per 8-k step: 4 ds_read_b128 (f16 a, wave-broadcast)
// + 4 global 16B (packed W, L2-hot) + 64 v_dot2_f32_f16.
// K=128: out = A0@W + bias (input projection; A0 = x16).
// K=256: z = [A0|A1]@W + bias; relu; + resid (f32 h_in); LayerNorm.
// In-place safety (middle layers: out==A1==resid rows): blocks own disjoint row
// sets; all reads (stage, resid) are own-row-only and precede the writes.

template <int K, bool FUSE, bool LAST>
__global__ __launch_bounds__(256) void gemmd_kernel(
    const f16* __restrict__ A0, const f16* __restrict__ A1,
    const f16* __restrict__ Wp,
    const float* __restrict__ bias, const float* __restrict__ lng, const float* __restrict__ lnb,
    const float* resid, float* out32, f16* out16, int N) {
    __shared__ f16 a_lds[32][K];

    const int tid = threadIdx.x;
    const int cq = tid & 31;
    const int rg = tid >> 5;
    const int row0 = blockIdx.x * 32;

    // stage A rows (f16, clamped for tail)
    constexpr int CPR = K / 8;
    for (int c = tid; c < 32 * CPR; c += 256) {
        int r = c / CPR;
        int col = (c % CPR) * 8;
        int gr = row0 + r;
        if (gr >= N) gr = N - 1;
        f16x8 v;
        if constexpr (K == 256) {
            if (col < HID) v = *(const f16x8*)(A0 + (size_t)gr * HID + col);
            else           v = *(const f16x8*)(A1 + (size_t)gr * HID + (col - HID));
        } else {
            v = *(const f16x8*)(A0 + (size_t)gr * HID + col);
        }
        *(f16x8*)&a_lds[r][col] = v;
    }
    __syncthreads();

    float acc[4][4] = {};

    #pragma unroll 2
    for (int k0 = 0; k0 < K; k0 += 8) {
        f16x8 a[4];
        #pragma unroll
        for (int j = 0; j < 4; j++) a[j] = *(const f16x8*)&a_lds[rg * 4 + j][k0];
        f16x8 w[4];
        #pragma unroll
        for (int p = 0; p < 4; p++)
            w[p] = *(const f16x8*)(Wp + ((size_t)(k0 / 2 + p) * HID + cq * 4) * 2);
        #pragma unroll
        for (int p = 0; p < 4; p++) {
            #pragma unroll
            for (int j = 0; j < 4; j++) {
                f16x2 ap;
                ap[0] = a[j][2 * p];
                ap[1] = a[j][2 * p + 1];
                #pragma unroll
                for (int c = 0; c < 4; c++) {
                    f16x2 wp2;
                    wp2[0] = w[p][2 * c];
                    wp2[1] = w[p][2 * c + 1];
                    acc[j][c] = dot2(ap, wp2, acc[j][c]);
                }
            }
        }
    }

    // epilogue
    f32x4 bv = *(const f32x4*)(bias + cq * 4);
    f32x4 gv = {}, lv = {};
    if constexpr (FUSE) {
        gv = *(const f32x4*)(lng + cq * 4);
        lv = *(const f32x4*)(lnb + cq * 4);
    }
    #pragma unroll
    for (int j = 0; j < 4; j++) {
        int gr = row0 + rg * 4 + j;
        int grc = (gr < N) ? gr : (N - 1);
        f32x4 z;
        #pragma unroll
        for (int c = 0; c < 4; c++) z[c] = acc[j][c] + bv[c];
        if constexpr (FUSE) {
            f32x4 res = *(const f32x4*)(resid + (size_t)grc * HID + cq * 4);
            #pragma unroll
            for (int c = 0; c < 4; c++) z[c] = fmaxf(z[c], 0.f) + res[c];
            // row LN: the row's 128 cols live in one aligned 32-lane group
            float s = z[0] + z[1] + z[2] + z[3];
            float s2 = z[0] * z[0] + z[1] * z[1] + z[2] * z[2] + z[3] * z[3];
            #pragma unroll
            for (int d = 1; d < 32; d <<= 1) {
                s += __shfl_xor(s, d);
                s2 += __shfl_xor(s2, d);
            }
            float mu = s * (1.f / 128.f);
            float var = s2 * (1.f / 128.f) - mu * mu;
            float rs = rsqrtf(var + 1e-5f);
            #pragma unroll
            for (int c = 0; c < 4; c++) z[c] = (z[c] - mu) * rs * gv[c] + lv[c];
        }
        if (gr < N) {
            if constexpr (LAST) {
                *(f32x4*)(out32 + (size_t)gr * HID + cq * 4) = z;
            } else {
                *(f32x4*)(out32 + (size_t)gr * HID + cq * 4) = z;
                f16x4 p;
                #pragma unroll
                for (int c = 0; c < 4; c++) p[c] = (f16)z[c];
                *(f16x4*)(out16 + (size_t)gr * HID + cq * 4) = p;
            }
        }
    }
}

// ---------------- launch ----------------

extern "C" void kernel_launch(void* const* d_in, const int* in_sizes, int n_in,
                              void* d_out, int out_size, void* d_ws, size_t ws_size,
                              hipStream_t stream) {
    const float* x = (const float*)d_in[0];
    const int* ei = (const int*)d_in[1];
    const float* inW = (const float*)d_in[2];
    const float* inb = (const float*)d_in[3];
    const float* Wl = (const float*)d_in[4];
    const float* bl = (const float*)d_in[5];
    const float* Wr = (const float*)d_in[6];
    const float* lng = (const float*)d_in[7];
    const float* lnb = (const float*)d_in[8];
    float* out = (float*)d_out;

    const int N = in_sizes[0] / HID;
    const int E = in_sizes[1] / 2;
    const int NL = 3;
    const int* src = ei;
    const int* dst = ei + E;

    char* w = (char*)d_ws;
    auto alloc = [&](size_t bytes) -> char* {
        char* p = w;
        w += (bytes + 255) & ~(size_t)255;
        return p;
    };
    int* degcnt = (int*)alloc((size_t)2 * N * 4);  // one alloc: single memset covers both
    int* deg = degcnt;
    int* cnt = degcnt + N;
    int* rowptr = (int*)alloc((N + 1) * 4);
    int* incl = (int*)alloc(N * 4);
    int* blksum = (int*)alloc(256 * 4);
    int* blkoff = (int*)alloc(256 * 4);
    int* colA = (int*)alloc((size_t)E * 4);
    float* invdeg = (float*)alloc(N * 4);
    f16* X16 = (f16*)alloc((size_t)N * HID * 2);      // f16 x (proj GEMM input)
    float* H32 = (float*)alloc((size_t)N * HID * 4);  // f32 h (residual path)
    f16* H16 = (f16*)alloc((size_t)N * HID * 2);      // f16 h (agg gather + GEMM A1)
    f16* AGG16 = (f16*)alloc((size_t)N * HID * 2);    // f16 aggregate (GEMM A0)
    f16* Wp0 = (f16*)alloc((size_t)64 * HID * 2 * 2);
    f16* WpL = (f16*)alloc((size_t)NL * HID * HID * 2 * 2);

    const int nbN = (N + 255) / 256;
    const int nbE = (E + 255) / 256;

    hipMemsetAsync(degcnt, 0, (size_t)2 * N * 4, stream);

    deg_kernel<<<nbE, 256, 0, stream>>>(dst, deg, E);
    scan1_kernel<<<nbN, 256, 0, stream>>>(deg, incl, blksum, N);
    scan2_kernel<<<1, 256, 0, stream>>>(blksum, blkoff, nbN);
    scan3_kernel<<<nbN, 256, 0, stream>>>(incl, deg, blkoff, rowptr, invdeg, N, E);
    fill_kernel<<<nbE, 256, 0, stream>>>(src, dst, rowptr, cnt, colA, E);
    // no sort: agg f32 sum order varies ~1e-6; validation is threshold-based

    const int n4 = N * HID / 4;
    cvtx_kernel<<<(n4 + 255) / 256, 256, 0, stream>>>(x, X16, n4);
    const int wslots = 64 * HID + NL * HID * HID;
    wpack_kernel<<<(wslots + 255) / 256, 256, 0, stream>>>(inW, Wl, Wr, Wp0, WpL, NL);

    const int gb = (N + 31) / 32;
    const int aggblocks = (N * 64 + 255) / 256;

    // input projection: h = x @ in_W + in_b  -> H32 + H16
    gemmd_kernel<128, false, false><<<gb, 256, 0, stream>>>(
        X16, nullptr, Wp0, inb, nullptr, nullptr, nullptr, H32, H16, N);

    for (int i = 0; i < NL; i++) {
        aggh_kernel<<<aggblocks, 256, 0, stream>>>(H16, rowptr, colA, invdeg, AGG16, N);
        const f16* wpi = WpL + (size_t)i * HID * HID * 2;
        if (i == NL - 1) {
            gemmd_kernel<256, true, true><<<gb, 256, 0, stream>>>(
                AGG16, H16, wpi, bl + i * HID, lng + i * HID, lnb + i * HID,
                H32, out, nullptr, N);
        } else {
            // in-place h update (own-rows-only reads precede writes)
            gemmd_kernel<256, true, false><<<gb, 256, 0, stream>>>(
                AGG16, H16, wpi, bl + i * HID, lng + i * HID, lnb + i * HID,
                H32, H32, H16, N);
        }
    }
}

// Round 8
// 330.161 us; speedup vs baseline: 1.9976x; 1.0199x over previous
//
#include <hip/hip_runtime.h>

// SAGEConv stack on MI355X — f16 storage + f32-accumulate dot2 pipeline.
// GEMM: 64-row blocks, 8x4/thread, packed-f16 v_dot2_f32_f16, W double-buffered.
// Aggregation: 4 edges per wave-instruction (16 lanes x 16B per neighbor row).
// h carried in f16 only (residual incl.); error budget 0.04-0.06 vs thr 0.133.

typedef _Float16 f16;
typedef __attribute__((ext_vector_type(2))) _Float16 f16x2;
typedef __attribute__((ext_vector_type(4))) _Float16 f16x4;
typedef __attribute__((ext_vector_type(8))) _Float16 f16x8;
typedef __attribute__((ext_vector_type(4))) float f32x4;

#define HID 128

static __device__ __forceinline__ float dot2(f16x2 a, f16x2 b, float c) {
#if __has_builtin(__builtin_amdgcn_fdot2)
    return __builtin_amdgcn_fdot2(a, b, c, false);
#else
    return c + (float)a[0] * (float)b[0] + (float)a[1] * (float)b[1];
#endif
}

// ---------------- CSR build ----------------

__global__ __launch_bounds__(256) void deg_kernel(const int* __restrict__ dst, int* __restrict__ deg, int E) {
    int e = blockIdx.x * 256 + threadIdx.x;
    if (e < E) atomicAdd(&deg[dst[e]], 1);
}

__global__ __launch_bounds__(256) void scan1_kernel(const int* __restrict__ deg, int* __restrict__ incl,
                                                    int* __restrict__ blksum, int N) {
    __shared__ int sm[256];
    int i = blockIdx.x * 256 + threadIdx.x;
    int v = (i < N) ? deg[i] : 0;
    sm[threadIdx.x] = v;
    __syncthreads();
    for (int d = 1; d < 256; d <<= 1) {
        int t = (threadIdx.x >= d) ? sm[threadIdx.x - d] : 0;
        __syncthreads();
        sm[threadIdx.x] += t;
        __syncthreads();
    }
    if (i < N) incl[i] = sm[threadIdx.x];
    if (threadIdx.x == 255) blksum[blockIdx.x] = sm[255];
}

__global__ __launch_bounds__(256) void scan2_kernel(const int* __restrict__ blksum, int* __restrict__ blkoff, int nb) {
    __shared__ int sm[256];
    int t = threadIdx.x;
    int v = (t < nb) ? blksum[t] : 0;
    sm[t] = v;
    __syncthreads();
    for (int d = 1; d < 256; d <<= 1) {
        int u = (t >= d) ? sm[t - d] : 0;
        __syncthreads();
        sm[t] += u;
        __syncthreads();
    }
    if (t < nb) blkoff[t] = sm[t] - v;  // exclusive
}

__global__ __launch_bounds__(256) void scan3_kernel(const int* __restrict__ incl, const int* __restrict__ deg,
                                                    const int* __restrict__ blkoff, int* __restrict__ rowptr,
                                                    int N, int E) {
    int i = blockIdx.x * 256 + threadIdx.x;
    if (i < N) rowptr[i] = incl[i] - deg[i] + blkoff[blockIdx.x];
    if (i == 0) rowptr[N] = E;
}

__global__ __launch_bounds__(256) void fill_kernel(const int* __restrict__ src, const int* __restrict__ dst,
                                                   const int* __restrict__ rowptr, int* __restrict__ cnt,
                                                   int* __restrict__ colA, int E) {
    int e = blockIdx.x * 256 + threadIdx.x;
    if (e < E) {
        int d = dst[e];
        int p = rowptr[d] + atomicAdd(&cnt[d], 1);
        colA[p] = src[e];
    }
}

// ---------------- W -> k-pair-interleaved f16 ----------------
// Wp layout: [kp][c][2] f16 — pair (W[2kp][c], W[2kp+1][c]).

__global__ __launch_bounds__(256) void wpack_kernel(const float* __restrict__ inW, const float* __restrict__ Wl,
                                                    const float* __restrict__ Wr, f16* __restrict__ Wp0,
                                                    f16* __restrict__ WpL, int nlayers) {
    int idx = blockIdx.x * 256 + threadIdx.x;
    int total = 64 * HID + nlayers * HID * HID;  // pair-slots
    if (idx >= total) return;
    if (idx < 64 * HID) {
        int kp = idx / HID, c = idx % HID;
        Wp0[idx * 2 + 0] = (f16)inW[(2 * kp) * HID + c];
        Wp0[idx * 2 + 1] = (f16)inW[(2 * kp + 1) * HID + c];
    } else {
        int r0 = idx - 64 * HID;
        int l = r0 / (HID * HID);
        int r = r0 % (HID * HID);
        int kp = r / HID, c = r % HID;
        int k0 = 2 * kp;
        const float* W = (k0 < HID) ? (Wl + (size_t)l * HID * HID + (size_t)k0 * HID)
                                    : (Wr + (size_t)l * HID * HID + (size_t)(k0 - HID) * HID);
        WpL[(size_t)r0 * 2 + 0] = (f16)W[c];
        WpL[(size_t)r0 * 2 + 1] = (f16)W[HID + c];
    }
}

// ---------------- mean aggregation: wave/node, 4 edges per load step ----------------
// Lane: grp = lane>>4 handles edge j0+grp; sub = lane&15 covers cols sub*8..+7
// (f16x8 = 16B). Manual x2 unroll -> 8 neighbor-row loads in flight per wave.
// Reduce over the 4 edge-groups with shfl_xor(16|32); lanes 0..15 write the row.

__global__ __launch_bounds__(256) void aggh_kernel(const f16* __restrict__ h16, const int* __restrict__ rowptr,
                                                   const int* __restrict__ colA,
                                                   f16* __restrict__ agg, int N) {
    int wid = blockIdx.x * 4 + (threadIdx.x >> 6);
    int lane = threadIdx.x & 63;
    if (wid >= N) return;
    int b = rowptr[wid], e = rowptr[wid + 1];
    int grp = lane >> 4, sub = lane & 15;
    float ax[8] = {};
    for (int j0 = b; j0 < e; j0 += 8) {
        int j1 = j0 + grp;
        int j2 = j0 + 4 + grp;
        f16x8 v1 = {}, v2 = {};
        if (j1 < e) v1 = *(const f16x8*)(h16 + (size_t)colA[j1] * HID + sub * 8);
        if (j2 < e) v2 = *(const f16x8*)(h16 + (size_t)colA[j2] * HID + sub * 8);
        #pragma unroll
        for (int i = 0; i < 8; i++) ax[i] += (float)v1[i] + (float)v2[i];
    }
    #pragma unroll
    for (int i = 0; i < 8; i++) {
        ax[i] += __shfl_xor(ax[i], 16);
        ax[i] += __shfl_xor(ax[i], 32);
    }
    if (lane < 16) {
        float id = 1.0f / (float)((e - b) > 1 ? (e - b) : 1);
        f16x8 o;
        #pragma unroll
        for (int i = 0; i < 8; i++) o[i] = (f16)(ax[i] * id);
        *(f16x8*)(agg + (size_t)wid * HID + sub * 8) = o;
    }
}

// ---------------- dot2-f16 GEMM: 64-row blocks, 8x4/thread, W double-buffer ----------------
// Block: 256 thr, 64 rows x 128 cols. Thread: cq=tid&31 -> cols 4cq..+3,
// rg=tid>>5 -> rows 8rg..+7. Per 8-k step: 8 ds_read_b128 (a) + 4 global 16B
// (W, prefetched one step ahead) + 128 v_dot2_f32_f16.
// K=128 (proj): A0 = x (f32, converted during stage), out = A@W + bias -> h16.
// K=256: z = [agg16|h16]@W + bias; relu; + resid16; LayerNorm -> h16 (or f32 out).
// In-place safety (out16==A1==resid16): blocks own disjoint 64-row sets; stage
// reads own rows pre-sync; resid (row,col) is read by the exact thread+iteration
// that writes it, after the read; LN shuffles are register-only.

template <int K, bool FUSE, bool LAST>
__global__ __launch_bounds__(256) void gemmd_kernel(
    const void* __restrict__ A0v, const f16* __restrict__ A1,
    const f16* __restrict__ Wp,
    const float* __restrict__ bias, const float* __restrict__ lng, const float* __restrict__ lnb,
    const f16* resid16, f16* out16, float* out32, int N) {
    __shared__ f16 a_lds[64][K];

    const int tid = threadIdx.x;
    const int cq = tid & 31;
    const int rg = tid >> 5;
    const int row0 = blockIdx.x * 64;

    // stage A rows (f16 in LDS; clamp tail rows)
    constexpr int CPR = K / 8;                 // 8-col chunks per row
    for (int c = tid; c < 64 * CPR; c += 256) {
        int r = c / CPR;
        int col = (c % CPR) * 8;
        int gr = row0 + r;
        if (gr >= N) gr = N - 1;
        f16x8 v;
        if constexpr (K == 256) {
            const f16* A0 = (const f16*)A0v;
            if (col < HID) v = *(const f16x8*)(A0 + (size_t)gr * HID + col);
            else           v = *(const f16x8*)(A1 + (size_t)gr * HID + (col - HID));
        } else {
            const float* xr = (const float*)A0v + (size_t)gr * HID + col;
            f32x4 v0 = *(const f32x4*)xr;
            f32x4 v1 = *(const f32x4*)(xr + 4);
            v[0] = (f16)v0[0]; v[1] = (f16)v0[1]; v[2] = (f16)v0[2]; v[3] = (f16)v0[3];
            v[4] = (f16)v1[0]; v[5] = (f16)v1[1]; v[6] = (f16)v1[2]; v[7] = (f16)v1[3];
        }
        *(f16x8*)&a_lds[r][col] = v;
    }
    __syncthreads();

    float acc[8][4] = {};
    f16x8 wcur[4];
    #pragma unroll
    for (int p = 0; p < 4; p++)
        wcur[p] = *(const f16x8*)(Wp + ((size_t)p * HID + cq * 4) * 2);

    #pragma unroll 2
    for (int k0 = 0; k0 < K; k0 += 8) {
        f16x8 w[4];
        #pragma unroll
        for (int p = 0; p < 4; p++) w[p] = wcur[p];
        if (k0 + 8 < K) {  // prefetch next step's W (one full step ~256cy ahead)
            #pragma unroll
            for (int p = 0; p < 4; p++)
                wcur[p] = *(const f16x8*)(Wp + ((size_t)((k0 + 8) / 2 + p) * HID + cq * 4) * 2);
        }
        f16x8 a[8];
        #pragma unroll
        for (int j = 0; j < 8; j++) a[j] = *(const f16x8*)&a_lds[rg * 8 + j][k0];
        #pragma unroll
        for (int p = 0; p < 4; p++) {
            #pragma unroll
            for (int j = 0; j < 8; j++) {
                f16x2 ap;
                ap[0] = a[j][2 * p];
                ap[1] = a[j][2 * p + 1];
                #pragma unroll
                for (int c = 0; c < 4; c++) {
                    f16x2 wp2;
                    wp2[0] = w[p][2 * c];
                    wp2[1] = w[p][2 * c + 1];
                    acc[j][c] = dot2(ap, wp2, acc[j][c]);
                }
            }
        }
    }

    // epilogue
    f32x4 bv = *(const f32x4*)(bias + cq * 4);
    f32x4 gv = {}, lv = {};
    if constexpr (FUSE) {
        gv = *(const f32x4*)(lng + cq * 4);
        lv = *(const f32x4*)(lnb + cq * 4);
    }
    #pragma unroll
    for (int j = 0; j < 8; j++) {
        int gr = row0 + rg * 8 + j;
        int grc = (gr < N) ? gr : (N - 1);
        f32x4 z;
        #pragma unroll
        for (int c = 0; c < 4; c++) z[c] = acc[j][c] + bv[c];
        if constexpr (FUSE) {
            f16x4 res = *(const f16x4*)(resid16 + (size_t)grc * HID + cq * 4);
            #pragma unroll
            for (int c = 0; c < 4; c++) z[c] = fmaxf(z[c], 0.f) + (float)res[c];
            // row LN: the row's 128 cols live in one aligned 32-lane group
            float s = z[0] + z[1] + z[2] + z[3];
            float s2 = z[0] * z[0] + z[1] * z[1] + z[2] * z[2] + z[3] * z[3];
            #pragma unroll
            for (int d = 1; d < 32; d <<= 1) {
                s += __shfl_xor(s, d);
                s2 += __shfl_xor(s2, d);
            }
            float mu = s * (1.f / 128.f);
            float var = s2 * (1.f / 128.f) - mu * mu;
            float rs = rsqrtf(var + 1e-5f);
            #pragma unroll
            for (int c = 0; c < 4; c++) z[c] = (z[c] - mu) * rs * gv[c] + lv[c];
        }
        if (gr < N) {
            if constexpr (LAST) {
                *(f32x4*)(out32 + (size_t)gr * HID + cq * 4) = z;
            } else {
                f16x4 p;
                #pragma unroll
                for (int c = 0; c < 4; c++) p[c] = (f16)z[c];
                *(f16x4*)(out16 + (size_t)gr * HID + cq * 4) = p;
            }
        }
    }
}

// ---------------- launch ----------------

extern "C" void kernel_launch(void* const* d_in, const int* in_sizes, int n_in,
                              void* d_out, int out_size, void* d_ws, size_t ws_size,
                              hipStream_t stream) {
    const float* x = (const float*)d_in[0];
    const int* ei = (const int*)d_in[1];
    const float* inW = (const float*)d_in[2];
    const float* inb = (const float*)d_in[3];
    const float* Wl = (const float*)d_in[4];
    const float* bl = (const float*)d_in[5];
    const float* Wr = (const float*)d_in[6];
    const float* lng = (const float*)d_in[7];
    const float* lnb = (const float*)d_in[8];
    float* out = (float*)d_out;

    const int N = in_sizes[0] / HID;
    const int E = in_sizes[1] / 2;
    const int NL = 3;
    const int* src = ei;
    const int* dst = ei + E;

    char* w = (char*)d_ws;
    auto alloc = [&](size_t bytes) -> char* {
        char* p = w;
        w += (bytes + 255) & ~(size_t)255;
        return p;
    };
    int* degcnt = (int*)alloc((size_t)2 * N * 4);  // one alloc: single memset covers both
    int* deg = degcnt;
    int* cnt = degcnt + N;
    int* rowptr = (int*)alloc((N + 1) * 4);
    int* incl = (int*)alloc(N * 4);
    int* blksum = (int*)alloc(256 * 4);
    int* blkoff = (int*)alloc(256 * 4);
    int* colA = (int*)alloc((size_t)E * 4);
    f16* H16 = (f16*)alloc((size_t)N * HID * 2);    // f16 h (all consumers)
    f16* AGG16 = (f16*)alloc((size_t)N * HID * 2);  // f16 aggregate
    f16* Wp0 = (f16*)alloc((size_t)64 * HID * 2 * 2);
    f16* WpL = (f16*)alloc((size_t)NL * HID * HID * 2 * 2);

    const int nbN = (N + 255) / 256;
    const int nbE = (E + 255) / 256;

    hipMemsetAsync(degcnt, 0, (size_t)2 * N * 4, stream);

    deg_kernel<<<nbE, 256, 0, stream>>>(dst, deg, E);
    scan1_kernel<<<nbN, 256, 0, stream>>>(deg, incl, blksum, N);
    scan2_kernel<<<1, 256, 0, stream>>>(blksum, blkoff, nbN);
    scan3_kernel<<<nbN, 256, 0, stream>>>(incl, deg, blkoff, rowptr, N, E);
    fill_kernel<<<nbE, 256, 0, stream>>>(src, dst, rowptr, cnt, colA, E);
    // no sort: agg f32 sum order varies ~1e-6; validation is threshold-based

    const int wslots = 64 * HID + NL * HID * HID;
    wpack_kernel<<<(wslots + 255) / 256, 256, 0, stream>>>(inW, Wl, Wr, Wp0, WpL, NL);

    const int gb = (N + 63) / 64;
    const int aggblocks = (N + 3) / 4;

    // input projection: h = x @ in_W + in_b  -> H16 (x converted during stage)
    gemmd_kernel<128, false, false><<<gb, 256, 0, stream>>>(
        x, nullptr, Wp0, inb, nullptr, nullptr, nullptr, H16, nullptr, N);

    for (int i = 0; i < NL; i++) {
        aggh_kernel<<<aggblocks, 256, 0, stream>>>(H16, rowptr, colA, AGG16, N);
        const f16* wpi = WpL + (size_t)i * HID * HID * 2;
        if (i == NL - 1) {
            gemmd_kernel<256, true, true><<<gb, 256, 0, stream>>>(
                AGG16, H16, wpi, bl + i * HID, lng + i * HID, lnb + i * HID,
                H16, nullptr, out, N);
        } else {
            // in-place h update (own-rows-only reads precede writes)
            gemmd_kernel<256, true, false><<<gb, 256, 0, stream>>>(
                AGG16, H16, wpi, bl + i * HID, lng + i * HID, lnb + i * HID,
                H16, H16, nullptr, N);
        }
    }
}